// Round 14
// baseline (143.119 us; speedup 1.0000x reference)
//
#include <hip/hip_runtime.h>

#define N_NODES 100000
#define F_IN 128
#define HID 64
#define OUT_F 300
#define WO_ROWS 320         // 300 padded to 20 tiles of 16
#define NBKT 782            // ceil(100000 / 128) buckets of 128 nodes
#define ECAP 2688           // fixed per-bucket segment (mean 2046, sigma 45 -> +14 sigma)
#define PART_BLOCKS 384
#define GEMM_BLOCKS 196     // ceil(100000 / 512), 8 waves x 64 nodes (r10/r13-proven)
#define SORT_CAP 4224       // >= ceil(1.6M/384) = 4167
#define EPT 9               // edges per thread in registers: 9*512 = 4608 >= 4167

typedef short bf8 __attribute__((ext_vector_type(8)));
typedef float f32x4 __attribute__((ext_vector_type(4)));

__device__ inline unsigned short f2bf(float f) {
    unsigned u = __builtin_bit_cast(unsigned, f);
    u += 0x7fff + ((u >> 16) & 1);          // round-to-nearest-even
    return (unsigned short)(u >> 16);
}
__device__ inline float b2f(unsigned short h) {
    return __builtin_bit_cast(float, (unsigned)h << 16);
}

// ------------------------------------------------------------------ prep: weights->bf16 + zero cursors
__global__ void k_prep(const float* __restrict__ Wl, const float* __restrict__ Wr,
                       const float* __restrict__ Wout,
                       unsigned short* __restrict__ Wc, unsigned short* __restrict__ Wo,
                       int* __restrict__ gcur) {
    int idx = blockIdx.x * blockDim.x + threadIdx.x;
    if (idx < 128 * 128) {
        int c = idx >> 7, k = idx & 127;
        float v = (c < HID) ? Wl[c * F_IN + k] : Wr[(c - HID) * F_IN + k];
        Wc[idx] = f2bf(v);
    } else if (idx < 128 * 128 + WO_ROWS * HID) {
        int j = idx - 128 * 128;
        int o = j >> 6, k = j & 63;
        Wo[j] = (o < OUT_F) ? f2bf(Wout[o * HID + k]) : (unsigned short)0;
    } else {
        int b = idx - 128 * 128 - WO_ROWS * HID;
        if (b < NBKT) gcur[b] = 0;
    }
}

// ------------------------------------------------------------------ merged partition + GEMM1, 512 threads
// Blocks [0,PART_BLOCKS): counting-sort partition, single-pass register-staged
// edge load (edges read from HBM exactly once).
// Blocks [PART_BLOCKS, +GEMM_BLOCKS): yz = x(bf16).Wc^T, 8 waves x 64 nodes,
// swapped-operand MFMA -> packed uint2 stores (4x fewer store instructions).
__global__ __launch_bounds__(512) void k_pg(const int* __restrict__ ei,
                                            int* __restrict__ gcur,
                                            unsigned* __restrict__ pedges, int nE,
                                            const float* __restrict__ x,
                                            const unsigned short* __restrict__ Wc,
                                            unsigned short* __restrict__ yz) {
    if (blockIdx.x < PART_BLOCKS) {
        // ---------------- counting-sort partition role ----------------
        __shared__ unsigned sorted[SORT_CAP];                 // 16.5 KB
        __shared__ int hcnt[1024], hoff[1024], hcur[1024];    // 12 KB (782 used)
        __shared__ int wpre[8];
        const int tid = threadIdx.x, lane = tid & 63, wid = tid >> 6;
        const int per = (nE + PART_BLOCKS - 1) / PART_BLOCKS;
        const int e0 = blockIdx.x * per;
        const int cnt = min(per, nE - e0);
        int mysrc[EPT], mydst[EPT];
        hcnt[tid * 2] = 0; hcnt[tid * 2 + 1] = 0;
        __syncthreads();
        // single-pass load + histogram (register staging, static indices)
#pragma unroll
        for (int m = 0; m < EPT; ++m) {
            int i = m * 512 + tid;
            if (i < cnt) {
                mydst[m] = ei[nE + e0 + i];
                mysrc[m] = ei[e0 + i];
                atomicAdd(&hcnt[mydst[m] >> 7], 1);
            }
        }
        // safety fallback for cnt > EPT*512 (never for nE=1.6M): direct scatter
        for (int i = EPT * 512 + tid; i < cnt; i += 512) {
            int src = ei[e0 + i], dst = ei[nE + e0 + i];
            int b = dst >> 7;
            int p = atomicAdd(&gcur[b], 1);
            if (p < ECAP) pedges[(size_t)b * ECAP + p] = ((unsigned)src << 7) | (unsigned)(dst & 127);
        }
        __syncthreads();
        // block scan of 1024 bins, 2 per thread
        int c0 = hcnt[tid * 2], c1 = hcnt[tid * 2 + 1];
        int tsum = c0 + c1;
        int s = tsum;
#pragma unroll
        for (int d = 1; d < 64; d <<= 1) { int t = __shfl_up(s, d, 64); if (lane >= d) s += t; }
        if (lane == 63) wpre[wid] = s;
        __syncthreads();
        if (tid == 0) { int run = 0; for (int w = 0; w < 8; ++w) { int t = wpre[w]; wpre[w] = run; run += t; } }
        __syncthreads();
        int excl = wpre[wid] + (s - tsum);
        hoff[tid * 2 + 0] = excl;       hcur[tid * 2 + 0] = excl;
        hoff[tid * 2 + 1] = excl + c0;  hcur[tid * 2 + 1] = excl + c0;
        __syncthreads();
        // scatter from registers into sorted order
#pragma unroll
        for (int m = 0; m < EPT; ++m) {
            int i = m * 512 + tid;
            if (i < cnt) {
                int p = atomicAdd(&hcur[mydst[m] >> 7], 1);
                sorted[p] = ((unsigned)mysrc[m] << 7) | (unsigned)(mydst[m] & 127);
            }
        }
        __syncthreads();
        // write out: one contiguous run per non-empty bucket
        for (int b = tid; b < NBKT; b += 512) {
            int c = hcnt[b];
            if (c > 0) {
                int gp = atomicAdd(&gcur[b], c);
                unsigned* dst = pedges + (size_t)b * ECAP + gp;
                int off = hoff[b];
                for (int i = 0; i < c; ++i) dst[i] = sorted[off + i];
            }
        }
    } else {
        // ---------------- GEMM1 role: 8 waves x 64-node tiles ----------------
        const int wv = threadIdx.x >> 6;
        const int nb = (blockIdx.x - PART_BLOCKS) * 512 + wv * 64;
        if (nb >= N_NODES) return;
        const int lane = threadIdx.x & 63;
        const int lm = lane & 15, lk = lane >> 4;

        f32x4 acc[4][8];
#pragma unroll
        for (int a = 0; a < 4; ++a)
#pragma unroll
            for (int b = 0; b < 8; ++b) acc[a][b] = f32x4{0.f, 0.f, 0.f, 0.f};

#pragma unroll
        for (int kt = 0; kt < 4; ++kt) {
            const int ko = kt * 32 + lk * 8;
            bf8 af[4], bw[8];
#pragma unroll
            for (int mt = 0; mt < 4; ++mt) {
                int row = nb + mt * 16 + lm;
                if (row >= N_NODES) row = N_NODES - 1;
                const float* xp = x + (size_t)row * F_IN + ko;
                float4 v0 = *(const float4*)xp;
                float4 v1 = *(const float4*)(xp + 4);
                bf8 t;
                t[0] = (short)f2bf(v0.x); t[1] = (short)f2bf(v0.y);
                t[2] = (short)f2bf(v0.z); t[3] = (short)f2bf(v0.w);
                t[4] = (short)f2bf(v1.x); t[5] = (short)f2bf(v1.y);
                t[6] = (short)f2bf(v1.z); t[7] = (short)f2bf(v1.w);
                af[mt] = t;
            }
#pragma unroll
            for (int nt = 0; nt < 8; ++nt)
                bw[nt] = *reinterpret_cast<const bf8*>(Wc + (nt * 16 + lm) * 128 + ko);
            // swapped operands: D col = node (lm), rows = 4 consecutive features
#pragma unroll
            for (int mt = 0; mt < 4; ++mt)
#pragma unroll
                for (int nt = 0; nt < 8; ++nt)
                    acc[mt][nt] = __builtin_amdgcn_mfma_f32_16x16x32_bf16(bw[nt], af[mt], acc[mt][nt], 0, 0, 0);
        }
        // packed stores: lane owns node (nb+mt*16+lm), feats nt*16+lk*4 .. +3
#pragma unroll
        for (int mt = 0; mt < 4; ++mt) {
            int node = nb + mt * 16 + lm;
            if (node < N_NODES) {
#pragma unroll
                for (int nt = 0; nt < 8; ++nt) {
                    uint2 v;
                    v.x = (unsigned)f2bf(acc[mt][nt][0]) | ((unsigned)f2bf(acc[mt][nt][1]) << 16);
                    v.y = (unsigned)f2bf(acc[mt][nt][2]) | ((unsigned)f2bf(acc[mt][nt][3]) << 16);
                    *(uint2*)(yz + (size_t)node * 128 + nt * 16 + lk * 4) = v;
                }
            }
        }
    }
}

// ------------------------------------------------------------------ bucket agg in y-space + h-formation (r12/r13 paired gather)
#define LOAD4(e) (*(const uint2*)(yz + (size_t)(e) * 128 + f4))
#define ACC(sv0, sv1, sv2, sv3, u) \
    sv0 += b2f(u.x & 0xffff); sv1 += b2f(u.x >> 16); \
    sv2 += b2f(u.y & 0xffff); sv3 += b2f(u.y >> 16);
__global__ __launch_bounds__(512) void k_agg3(const unsigned short* __restrict__ yz,
                                              const unsigned* __restrict__ pedges,
                                              const int* __restrict__ gcur,
                                              const float* __restrict__ bl,
                                              unsigned short* __restrict__ h) {
    __shared__ unsigned esrc[ECAP];          // 10.5 KB
    __shared__ int hcnt[128], hoff[128], hcur[128];
    const int tid = threadIdx.x, lane = tid & 63, wv = tid >> 6;
    const int bkt = blockIdx.x;
    int cnt = gcur[bkt]; if (cnt > ECAP) cnt = ECAP;
    const size_t base = (size_t)bkt * ECAP;
    if (tid < 128) hcnt[tid] = 0;
    __syncthreads();
    for (int i = tid; i < cnt; i += 512)
        atomicAdd(&hcnt[pedges[base + i] & 127], 1);
    __syncthreads();
    if (tid < 64) {
        int a = hcnt[2 * tid], b = hcnt[2 * tid + 1];
        int s = a + b;
#pragma unroll
        for (int d = 1; d < 64; d <<= 1) { int t = __shfl_up(s, d, 64); if (lane >= d) s += t; }
        int ex = s - (a + b);
        hoff[2 * tid] = ex;     hcur[2 * tid] = ex;
        hoff[2 * tid + 1] = ex + a; hcur[2 * tid + 1] = ex + a;
    }
    __syncthreads();
    for (int i = tid; i < cnt; i += 512) {
        unsigned e = pedges[base + i];
        int p = atomicAdd(&hcur[e & 127], 1);
        esrc[p] = e >> 7;
    }
    __syncthreads();
    const int q = lane >> 4;                 // edge slot of the quad
    const int f4 = (lane & 15) * 4;          // 4 features owned by this lane
    float4 blv = *(const float4*)(bl + f4);
    for (int lp = 0; lp < 8; ++lp) {
        const int locA = wv * 16 + 2 * lp, locB = locA + 1;
        const int nodeA = bkt * 128 + locA, nodeB = nodeA + 1;
        const int stA = hoff[locA], dgA = hcnt[locA];
        const int stB = hoff[locB], dgB = hcnt[locB];
        float a0 = 0.f, a1 = 0.f, a2 = 0.f, a3 = 0.f;
        float b0 = 0.f, b1 = 0.f, b2 = 0.f, b3 = 0.f;
        int jA = 0, jB = 0;
        while (jA + 8 <= dgA && jB + 8 <= dgB) {
            unsigned eA0 = esrc[stA + jA + q],  eA1 = esrc[stA + jA + 4 + q];
            unsigned eB0 = esrc[stB + jB + q],  eB1 = esrc[stB + jB + 4 + q];
            uint2 uA0 = LOAD4(eA0), uA1 = LOAD4(eA1);
            uint2 uB0 = LOAD4(eB0), uB1 = LOAD4(eB1);
            ACC(a0, a1, a2, a3, uA0) ACC(a0, a1, a2, a3, uA1)
            ACC(b0, b1, b2, b3, uB0) ACC(b0, b1, b2, b3, uB1)
            jA += 8; jB += 8;
        }
        while (jA + 8 <= dgA) {
            unsigned eA0 = esrc[stA + jA + q], eA1 = esrc[stA + jA + 4 + q];
            uint2 uA0 = LOAD4(eA0), uA1 = LOAD4(eA1);
            ACC(a0, a1, a2, a3, uA0) ACC(a0, a1, a2, a3, uA1)
            jA += 8;
        }
        while (jB + 8 <= dgB) {
            unsigned eB0 = esrc[stB + jB + q], eB1 = esrc[stB + jB + 4 + q];
            uint2 uB0 = LOAD4(eB0), uB1 = LOAD4(eB1);
            ACC(b0, b1, b2, b3, uB0) ACC(b0, b1, b2, b3, uB1)
            jB += 8;
        }
        if (jA + 4 <= dgA) {
            uint2 u = LOAD4(esrc[stA + jA + q]);
            ACC(a0, a1, a2, a3, u)
            jA += 4;
        }
        if (jB + 4 <= dgB) {
            uint2 u = LOAD4(esrc[stB + jB + q]);
            ACC(b0, b1, b2, b3, u)
            jB += 4;
        }
        if (q < dgA - jA) {
            uint2 u = LOAD4(esrc[stA + jA + q]);
            ACC(a0, a1, a2, a3, u)
        }
        if (q < dgB - jB) {
            uint2 u = LOAD4(esrc[stB + jB + q]);
            ACC(b0, b1, b2, b3, u)
        }
        a0 += __shfl_xor(a0, 16); a0 += __shfl_xor(a0, 32);
        a1 += __shfl_xor(a1, 16); a1 += __shfl_xor(a1, 32);
        a2 += __shfl_xor(a2, 16); a2 += __shfl_xor(a2, 32);
        a3 += __shfl_xor(a3, 16); a3 += __shfl_xor(a3, 32);
        b0 += __shfl_xor(b0, 16); b0 += __shfl_xor(b0, 32);
        b1 += __shfl_xor(b1, 16); b1 += __shfl_xor(b1, 32);
        b2 += __shfl_xor(b2, 16); b2 += __shfl_xor(b2, 32);
        b3 += __shfl_xor(b3, 16); b3 += __shfl_xor(b3, 32);
        if (q == 0) {
            if (nodeA < N_NODES) {
                float inv = 1.0f / fmaxf((float)dgA, 1.0f);
                uint2 zu = *(const uint2*)(yz + (size_t)nodeA * 128 + HID + f4);
                float v0 = a0 * inv + b2f(zu.x & 0xffff) + blv.x;
                float v1 = a1 * inv + b2f(zu.x >> 16)    + blv.y;
                float v2 = a2 * inv + b2f(zu.y & 0xffff) + blv.z;
                float v3 = a3 * inv + b2f(zu.y >> 16)    + blv.w;
                uint2 hv;
                hv.x = (unsigned)f2bf(fmaxf(v0, 0.f)) | ((unsigned)f2bf(fmaxf(v1, 0.f)) << 16);
                hv.y = (unsigned)f2bf(fmaxf(v2, 0.f)) | ((unsigned)f2bf(fmaxf(v3, 0.f)) << 16);
                *(uint2*)(h + (size_t)nodeA * HID + f4) = hv;
            }
            if (nodeB < N_NODES) {
                float inv = 1.0f / fmaxf((float)dgB, 1.0f);
                uint2 zu = *(const uint2*)(yz + (size_t)nodeB * 128 + HID + f4);
                float v0 = b0 * inv + b2f(zu.x & 0xffff) + blv.x;
                float v1 = b1 * inv + b2f(zu.x >> 16)    + blv.y;
                float v2 = b2 * inv + b2f(zu.y & 0xffff) + blv.z;
                float v3 = b3 * inv + b2f(zu.y >> 16)    + blv.w;
                uint2 hv;
                hv.x = (unsigned)f2bf(fmaxf(v0, 0.f)) | ((unsigned)f2bf(fmaxf(v1, 0.f)) << 16);
                hv.y = (unsigned)f2bf(fmaxf(v2, 0.f)) | ((unsigned)f2bf(fmaxf(v3, 0.f)) << 16);
                *(uint2*)(h + (size_t)nodeB * HID + f4) = hv;
            }
        }
    }
}

// ------------------------------------------------------------------ fused3: out = h.Wo^T + bout (r12/r13, LDS-free swapped-store)
__global__ __launch_bounds__(256) void k_fused3(
    const unsigned short* __restrict__ h, const unsigned short* __restrict__ Wo,
    const float* __restrict__ bout, float* __restrict__ out) {

    const int tid = threadIdx.x;
    const int lane = tid & 63;
    const int wv = tid >> 6;
    const int lm = lane & 15, lk = lane >> 4;
    const int node_g = blockIdx.x * 64 + wv * 16 + lm;
    int row = (node_g < N_NODES) ? node_g : (N_NODES - 1);

    bf8 ah[2];
#pragma unroll
    for (int k2 = 0; k2 < 2; ++k2)
        ah[k2] = *reinterpret_cast<const bf8*>(h + (size_t)row * HID + k2 * 32 + lk * 8);

    for (int g = 0; g < 5; ++g) {
        f32x4 acc2[4];
#pragma unroll
        for (int b = 0; b < 4; ++b) acc2[b] = f32x4{0.f, 0.f, 0.f, 0.f};
#pragma unroll
        for (int k2 = 0; k2 < 2; ++k2) {
            bf8 bw[4];
#pragma unroll
            for (int nt = 0; nt < 4; ++nt)
                bw[nt] = *reinterpret_cast<const bf8*>(
                    Wo + (size_t)((g * 4 + nt) * 16 + lm) * HID + k2 * 32 + lk * 8);
#pragma unroll
            for (int nt = 0; nt < 4; ++nt)
                acc2[nt] = __builtin_amdgcn_mfma_f32_16x16x32_bf16(bw[nt], ah[k2], acc2[nt], 0, 0, 0);
        }
#pragma unroll
        for (int nt = 0; nt < 4; ++nt) {
            int ob = (g * 4 + nt) * 16 + lk * 4;
            if (ob < OUT_F && node_g < N_NODES) {
                float4 bo = *(const float4*)(bout + ob);
                float4 v;
                v.x = acc2[nt][0] + bo.x;
                v.y = acc2[nt][1] + bo.y;
                v.z = acc2[nt][2] + bo.z;
                v.w = acc2[nt][3] + bo.w;
                *(float4*)(out + (size_t)node_g * OUT_F + ob) = v;
            }
        }
    }
}

extern "C" void kernel_launch(void* const* d_in, const int* in_sizes, int n_in,
                              void* d_out, int out_size, void* d_ws, size_t ws_size,
                              hipStream_t stream) {
    const float* x    = (const float*)d_in[0];
    const int*   ei   = (const int*)d_in[1];
    const float* Wl   = (const float*)d_in[2];
    const float* bl   = (const float*)d_in[3];
    const float* Wr   = (const float*)d_in[4];
    const float* Wout = (const float*)d_in[5];
    const float* bout = (const float*)d_in[6];
    float* out = (float*)d_out;

    int nE = in_sizes[1] / 2;

    unsigned short* yz = (unsigned short*)d_ws;                   // 25.6 MB
    unsigned short* h  = yz + (size_t)N_NODES * 128;              // 12.8 MB
    unsigned* pedges = (unsigned*)(h + (size_t)N_NODES * HID);    // 8.41 MB (NBKT*ECAP)
    int* gcur  = (int*)(pedges + (size_t)NBKT * ECAP);
    unsigned short* Wc = (unsigned short*)(gcur + NBKT);          // 128*128
    unsigned short* Wo = Wc + 128 * 128;                          // 320*64

    int prep_n = 128 * 128 + WO_ROWS * HID + NBKT;
    k_prep<<<(prep_n + 255) / 256, 256, 0, stream>>>(Wl, Wr, Wout, Wc, Wo, gcur);
    k_pg<<<PART_BLOCKS + GEMM_BLOCKS, 512, 0, stream>>>(ei, gcur, pedges, nE, x, Wc, yz);
    k_agg3<<<NBKT, 512, 0, stream>>>(yz, pedges, gcur, bl, h);
    k_fused3<<<(N_NODES + 63) / 64, 256, 0, stream>>>(h, Wo, bout, out);
}

// Round 15
// 135.019 us; speedup vs baseline: 1.0600x; 1.0600x over previous
//
#include <hip/hip_runtime.h>

#define N_NODES 100000
#define F_IN 128
#define HID 64
#define OUT_F 300
#define WO_ROWS 320         // 300 padded to 20 tiles of 16
#define NBKT 782            // ceil(100000 / 128) buckets of 128 nodes
#define ECAP 2688           // fixed per-bucket segment (mean 2046, sigma 45 -> +14 sigma)
#define PART_BLOCKS 256     // exactly 1 block/CU after GEMM drains (140 VGPR -> 1x512thr/CU)
#define GEMM_BLOCKS 196     // ceil(100000 / 512), 8 waves x 64 nodes (r10/r13-proven)
#define SORT_CAP 6400       // per-chunk LDS sort capacity (>= ceil(1.6M/256))

typedef short bf8 __attribute__((ext_vector_type(8)));
typedef float f32x4 __attribute__((ext_vector_type(4)));

__device__ inline unsigned short f2bf(float f) {
    unsigned u = __builtin_bit_cast(unsigned, f);
    u += 0x7fff + ((u >> 16) & 1);          // round-to-nearest-even
    return (unsigned short)(u >> 16);
}
__device__ inline float b2f(unsigned short h) {
    return __builtin_bit_cast(float, (unsigned)h << 16);
}

// ------------------------------------------------------------------ prep: weights->bf16 + zero cursors
__global__ void k_prep(const float* __restrict__ Wl, const float* __restrict__ Wr,
                       const float* __restrict__ Wout,
                       unsigned short* __restrict__ Wc, unsigned short* __restrict__ Wo,
                       int* __restrict__ gcur) {
    int idx = blockIdx.x * blockDim.x + threadIdx.x;
    if (idx < 128 * 128) {
        int c = idx >> 7, k = idx & 127;
        float v = (c < HID) ? Wl[c * F_IN + k] : Wr[(c - HID) * F_IN + k];
        Wc[idx] = f2bf(v);
    } else if (idx < 128 * 128 + WO_ROWS * HID) {
        int j = idx - 128 * 128;
        int o = j >> 6, k = j & 63;
        Wo[j] = (o < OUT_F) ? f2bf(Wout[o * HID + k]) : (unsigned short)0;
    } else {
        int b = idx - 128 * 128 - WO_ROWS * HID;
        if (b < NBKT) gcur[b] = 0;
    }
}

// ------------------------------------------------------------------ merged partition + GEMM1, 512 threads (r13 exact)
// Blocks [0,PART_BLOCKS): two-pass LDS counting-sort partition.
// Blocks [PART_BLOCKS, +GEMM_BLOCKS): yz = x(bf16).Wc^T, 8 waves x 64 nodes,
// normal operand order -> lm indexes feature -> 32B-coalesced scalar stores.
__global__ __launch_bounds__(512) void k_pg(const int* __restrict__ ei,
                                            int* __restrict__ gcur,
                                            unsigned* __restrict__ pedges, int nE,
                                            const float* __restrict__ x,
                                            const unsigned short* __restrict__ Wc,
                                            unsigned short* __restrict__ yz) {
    if (blockIdx.x < PART_BLOCKS) {
        // ---------------- counting-sort partition role ----------------
        __shared__ unsigned sorted[SORT_CAP];    // 25.6 KB
        __shared__ int hcnt[1024], hoff[1024], hcur[1024];   // 12 KB (782 used)
        __shared__ int wpre[8];
        const int tid = threadIdx.x, lane = tid & 63, wid = tid >> 6;
        const int per = (nE + PART_BLOCKS - 1) / PART_BLOCKS;
        const int e0 = blockIdx.x * per;
        const int e1 = min(e0 + per, nE);
        for (int cb = e0; cb < e1; cb += SORT_CAP) {
            const int cnt = min(SORT_CAP, e1 - cb);
            hcnt[tid * 2] = 0; hcnt[tid * 2 + 1] = 0;
            __syncthreads();
            for (int i = tid; i < cnt; i += 512)
                atomicAdd(&hcnt[ei[nE + cb + i] >> 7], 1);
            __syncthreads();
            int c0 = hcnt[tid * 2], c1 = hcnt[tid * 2 + 1];
            int tsum = c0 + c1;
            int s = tsum;
#pragma unroll
            for (int d = 1; d < 64; d <<= 1) { int t = __shfl_up(s, d, 64); if (lane >= d) s += t; }
            if (lane == 63) wpre[wid] = s;
            __syncthreads();
            if (tid == 0) { int run = 0; for (int w = 0; w < 8; ++w) { int t = wpre[w]; wpre[w] = run; run += t; } }
            __syncthreads();
            int excl = wpre[wid] + (s - tsum);
            hoff[tid * 2 + 0] = excl;       hcur[tid * 2 + 0] = excl;
            hoff[tid * 2 + 1] = excl + c0;  hcur[tid * 2 + 1] = excl + c0;
            __syncthreads();
            for (int i = tid; i < cnt; i += 512) {
                int src = ei[cb + i];
                int dst = ei[nE + cb + i];
                unsigned pk = ((unsigned)src << 7) | (unsigned)(dst & 127);
                int p = atomicAdd(&hcur[dst >> 7], 1);
                sorted[p] = pk;
            }
            __syncthreads();
            for (int b = tid; b < NBKT; b += 512) {
                int c = hcnt[b];
                if (c > 0) {
                    int gp = atomicAdd(&gcur[b], c);
                    unsigned* dst = pedges + (size_t)b * ECAP + gp;
                    int off = hoff[b];
                    for (int i = 0; i < c; ++i) dst[i] = sorted[off + i];
                }
            }
            __syncthreads();
        }
    } else {
        // ---------------- GEMM1 role: 8 waves x 64-node tiles (r10) ----------------
        const int wv = threadIdx.x >> 6;
        const int nb = (blockIdx.x - PART_BLOCKS) * 512 + wv * 64;
        if (nb >= N_NODES) return;
        const int lane = threadIdx.x & 63;
        const int lm = lane & 15, lk = lane >> 4;

        f32x4 acc[4][8];
#pragma unroll
        for (int a = 0; a < 4; ++a)
#pragma unroll
            for (int b = 0; b < 8; ++b) acc[a][b] = f32x4{0.f, 0.f, 0.f, 0.f};

#pragma unroll
        for (int kt = 0; kt < 4; ++kt) {
            const int ko = kt * 32 + lk * 8;
            bf8 af[4], bw[8];
#pragma unroll
            for (int mt = 0; mt < 4; ++mt) {
                int row = nb + mt * 16 + lm;
                if (row >= N_NODES) row = N_NODES - 1;
                const float* xp = x + (size_t)row * F_IN + ko;
                float4 v0 = *(const float4*)xp;
                float4 v1 = *(const float4*)(xp + 4);
                bf8 t;
                t[0] = (short)f2bf(v0.x); t[1] = (short)f2bf(v0.y);
                t[2] = (short)f2bf(v0.z); t[3] = (short)f2bf(v0.w);
                t[4] = (short)f2bf(v1.x); t[5] = (short)f2bf(v1.y);
                t[6] = (short)f2bf(v1.z); t[7] = (short)f2bf(v1.w);
                af[mt] = t;
            }
#pragma unroll
            for (int nt = 0; nt < 8; ++nt)
                bw[nt] = *reinterpret_cast<const bf8*>(Wc + (nt * 16 + lm) * 128 + ko);
#pragma unroll
            for (int mt = 0; mt < 4; ++mt)
#pragma unroll
                for (int nt = 0; nt < 8; ++nt)
                    acc[mt][nt] = __builtin_amdgcn_mfma_f32_16x16x32_bf16(af[mt], bw[nt], acc[mt][nt], 0, 0, 0);
        }
#pragma unroll
        for (int mt = 0; mt < 4; ++mt)
#pragma unroll
            for (int r = 0; r < 4; ++r) {
                int node = nb + mt * 16 + lk * 4 + r;
                if (node < N_NODES) {
#pragma unroll
                    for (int nt = 0; nt < 8; ++nt)
                        yz[(size_t)node * 128 + nt * 16 + lm] = f2bf(acc[mt][nt][r]);
                }
            }
    }
}

// ------------------------------------------------------------------ bucket agg in y-space + h-formation (r12/r13 paired gather)
#define LOAD4(e) (*(const uint2*)(yz + (size_t)(e) * 128 + f4))
#define ACC(sv0, sv1, sv2, sv3, u) \
    sv0 += b2f(u.x & 0xffff); sv1 += b2f(u.x >> 16); \
    sv2 += b2f(u.y & 0xffff); sv3 += b2f(u.y >> 16);
__global__ __launch_bounds__(512) void k_agg3(const unsigned short* __restrict__ yz,
                                              const unsigned* __restrict__ pedges,
                                              const int* __restrict__ gcur,
                                              const float* __restrict__ bl,
                                              unsigned short* __restrict__ h) {
    __shared__ unsigned esrc[ECAP];          // 10.5 KB
    __shared__ int hcnt[128], hoff[128], hcur[128];
    const int tid = threadIdx.x, lane = tid & 63, wv = tid >> 6;
    const int bkt = blockIdx.x;
    int cnt = gcur[bkt]; if (cnt > ECAP) cnt = ECAP;
    const size_t base = (size_t)bkt * ECAP;
    if (tid < 128) hcnt[tid] = 0;
    __syncthreads();
    for (int i = tid; i < cnt; i += 512)
        atomicAdd(&hcnt[pedges[base + i] & 127], 1);
    __syncthreads();
    if (tid < 64) {
        int a = hcnt[2 * tid], b = hcnt[2 * tid + 1];
        int s = a + b;
#pragma unroll
        for (int d = 1; d < 64; d <<= 1) { int t = __shfl_up(s, d, 64); if (lane >= d) s += t; }
        int ex = s - (a + b);
        hoff[2 * tid] = ex;     hcur[2 * tid] = ex;
        hoff[2 * tid + 1] = ex + a; hcur[2 * tid + 1] = ex + a;
    }
    __syncthreads();
    for (int i = tid; i < cnt; i += 512) {
        unsigned e = pedges[base + i];
        int p = atomicAdd(&hcur[e & 127], 1);
        esrc[p] = e >> 7;
    }
    __syncthreads();
    const int q = lane >> 4;                 // edge slot of the quad
    const int f4 = (lane & 15) * 4;          // 4 features owned by this lane
    float4 blv = *(const float4*)(bl + f4);
    for (int lp = 0; lp < 8; ++lp) {
        const int locA = wv * 16 + 2 * lp, locB = locA + 1;
        const int nodeA = bkt * 128 + locA, nodeB = nodeA + 1;
        const int stA = hoff[locA], dgA = hcnt[locA];
        const int stB = hoff[locB], dgB = hcnt[locB];
        float a0 = 0.f, a1 = 0.f, a2 = 0.f, a3 = 0.f;
        float b0 = 0.f, b1 = 0.f, b2 = 0.f, b3 = 0.f;
        int jA = 0, jB = 0;
        while (jA + 8 <= dgA && jB + 8 <= dgB) {
            unsigned eA0 = esrc[stA + jA + q],  eA1 = esrc[stA + jA + 4 + q];
            unsigned eB0 = esrc[stB + jB + q],  eB1 = esrc[stB + jB + 4 + q];
            uint2 uA0 = LOAD4(eA0), uA1 = LOAD4(eA1);
            uint2 uB0 = LOAD4(eB0), uB1 = LOAD4(eB1);
            ACC(a0, a1, a2, a3, uA0) ACC(a0, a1, a2, a3, uA1)
            ACC(b0, b1, b2, b3, uB0) ACC(b0, b1, b2, b3, uB1)
            jA += 8; jB += 8;
        }
        while (jA + 8 <= dgA) {
            unsigned eA0 = esrc[stA + jA + q], eA1 = esrc[stA + jA + 4 + q];
            uint2 uA0 = LOAD4(eA0), uA1 = LOAD4(eA1);
            ACC(a0, a1, a2, a3, uA0) ACC(a0, a1, a2, a3, uA1)
            jA += 8;
        }
        while (jB + 8 <= dgB) {
            unsigned eB0 = esrc[stB + jB + q], eB1 = esrc[stB + jB + 4 + q];
            uint2 uB0 = LOAD4(eB0), uB1 = LOAD4(eB1);
            ACC(b0, b1, b2, b3, uB0) ACC(b0, b1, b2, b3, uB1)
            jB += 8;
        }
        if (jA + 4 <= dgA) {
            uint2 u = LOAD4(esrc[stA + jA + q]);
            ACC(a0, a1, a2, a3, u)
            jA += 4;
        }
        if (jB + 4 <= dgB) {
            uint2 u = LOAD4(esrc[stB + jB + q]);
            ACC(b0, b1, b2, b3, u)
            jB += 4;
        }
        if (q < dgA - jA) {
            uint2 u = LOAD4(esrc[stA + jA + q]);
            ACC(a0, a1, a2, a3, u)
        }
        if (q < dgB - jB) {
            uint2 u = LOAD4(esrc[stB + jB + q]);
            ACC(b0, b1, b2, b3, u)
        }
        a0 += __shfl_xor(a0, 16); a0 += __shfl_xor(a0, 32);
        a1 += __shfl_xor(a1, 16); a1 += __shfl_xor(a1, 32);
        a2 += __shfl_xor(a2, 16); a2 += __shfl_xor(a2, 32);
        a3 += __shfl_xor(a3, 16); a3 += __shfl_xor(a3, 32);
        b0 += __shfl_xor(b0, 16); b0 += __shfl_xor(b0, 32);
        b1 += __shfl_xor(b1, 16); b1 += __shfl_xor(b1, 32);
        b2 += __shfl_xor(b2, 16); b2 += __shfl_xor(b2, 32);
        b3 += __shfl_xor(b3, 16); b3 += __shfl_xor(b3, 32);
        if (q == 0) {
            if (nodeA < N_NODES) {
                float inv = 1.0f / fmaxf((float)dgA, 1.0f);
                uint2 zu = *(const uint2*)(yz + (size_t)nodeA * 128 + HID + f4);
                float v0 = a0 * inv + b2f(zu.x & 0xffff) + blv.x;
                float v1 = a1 * inv + b2f(zu.x >> 16)    + blv.y;
                float v2 = a2 * inv + b2f(zu.y & 0xffff) + blv.z;
                float v3 = a3 * inv + b2f(zu.y >> 16)    + blv.w;
                uint2 hv;
                hv.x = (unsigned)f2bf(fmaxf(v0, 0.f)) | ((unsigned)f2bf(fmaxf(v1, 0.f)) << 16);
                hv.y = (unsigned)f2bf(fmaxf(v2, 0.f)) | ((unsigned)f2bf(fmaxf(v3, 0.f)) << 16);
                *(uint2*)(h + (size_t)nodeA * HID + f4) = hv;
            }
            if (nodeB < N_NODES) {
                float inv = 1.0f / fmaxf((float)dgB, 1.0f);
                uint2 zu = *(const uint2*)(yz + (size_t)nodeB * 128 + HID + f4);
                float v0 = b0 * inv + b2f(zu.x & 0xffff) + blv.x;
                float v1 = b1 * inv + b2f(zu.x >> 16)    + blv.y;
                float v2 = b2 * inv + b2f(zu.y & 0xffff) + blv.z;
                float v3 = b3 * inv + b2f(zu.y >> 16)    + blv.w;
                uint2 hv;
                hv.x = (unsigned)f2bf(fmaxf(v0, 0.f)) | ((unsigned)f2bf(fmaxf(v1, 0.f)) << 16);
                hv.y = (unsigned)f2bf(fmaxf(v2, 0.f)) | ((unsigned)f2bf(fmaxf(v3, 0.f)) << 16);
                *(uint2*)(h + (size_t)nodeB * HID + f4) = hv;
            }
        }
    }
}

// ------------------------------------------------------------------ fused3: out = h.Wo^T + bout (r12/r13, LDS-free swapped-store)
__global__ __launch_bounds__(256) void k_fused3(
    const unsigned short* __restrict__ h, const unsigned short* __restrict__ Wo,
    const float* __restrict__ bout, float* __restrict__ out) {

    const int tid = threadIdx.x;
    const int lane = tid & 63;
    const int wv = tid >> 6;
    const int lm = lane & 15, lk = lane >> 4;
    const int node_g = blockIdx.x * 64 + wv * 16 + lm;
    int row = (node_g < N_NODES) ? node_g : (N_NODES - 1);

    bf8 ah[2];
#pragma unroll
    for (int k2 = 0; k2 < 2; ++k2)
        ah[k2] = *reinterpret_cast<const bf8*>(h + (size_t)row * HID + k2 * 32 + lk * 8);

    for (int g = 0; g < 5; ++g) {
        f32x4 acc2[4];
#pragma unroll
        for (int b = 0; b < 4; ++b) acc2[b] = f32x4{0.f, 0.f, 0.f, 0.f};
#pragma unroll
        for (int k2 = 0; k2 < 2; ++k2) {
            bf8 bw[4];
#pragma unroll
            for (int nt = 0; nt < 4; ++nt)
                bw[nt] = *reinterpret_cast<const bf8*>(
                    Wo + (size_t)((g * 4 + nt) * 16 + lm) * HID + k2 * 32 + lk * 8);
#pragma unroll
            for (int nt = 0; nt < 4; ++nt)
                acc2[nt] = __builtin_amdgcn_mfma_f32_16x16x32_bf16(bw[nt], ah[k2], acc2[nt], 0, 0, 0);
        }
#pragma unroll
        for (int nt = 0; nt < 4; ++nt) {
            int ob = (g * 4 + nt) * 16 + lk * 4;
            if (ob < OUT_F && node_g < N_NODES) {
                float4 bo = *(const float4*)(bout + ob);
                float4 v;
                v.x = acc2[nt][0] + bo.x;
                v.y = acc2[nt][1] + bo.y;
                v.z = acc2[nt][2] + bo.z;
                v.w = acc2[nt][3] + bo.w;
                *(float4*)(out + (size_t)node_g * OUT_F + ob) = v;
            }
        }
    }
}

extern "C" void kernel_launch(void* const* d_in, const int* in_sizes, int n_in,
                              void* d_out, int out_size, void* d_ws, size_t ws_size,
                              hipStream_t stream) {
    const float* x    = (const float*)d_in[0];
    const int*   ei   = (const int*)d_in[1];
    const float* Wl   = (const float*)d_in[2];
    const float* bl   = (const float*)d_in[3];
    const float* Wr   = (const float*)d_in[4];
    const float* Wout = (const float*)d_in[5];
    const float* bout = (const float*)d_in[6];
    float* out = (float*)d_out;

    int nE = in_sizes[1] / 2;

    unsigned short* yz = (unsigned short*)d_ws;                   // 25.6 MB
    unsigned short* h  = yz + (size_t)N_NODES * 128;              // 12.8 MB
    unsigned* pedges = (unsigned*)(h + (size_t)N_NODES * HID);    // 8.41 MB (NBKT*ECAP)
    int* gcur  = (int*)(pedges + (size_t)NBKT * ECAP);
    unsigned short* Wc = (unsigned short*)(gcur + NBKT);          // 128*128
    unsigned short* Wo = Wc + 128 * 128;                          // 320*64

    int prep_n = 128 * 128 + WO_ROWS * HID + NBKT;
    k_prep<<<(prep_n + 255) / 256, 256, 0, stream>>>(Wl, Wr, Wout, Wc, Wo, gcur);
    k_pg<<<PART_BLOCKS + GEMM_BLOCKS, 512, 0, stream>>>(ei, gcur, pedges, nE, x, Wc, yz);
    k_agg3<<<NBKT, 512, 0, stream>>>(yz, pedges, gcur, bl, h);
    k_fused3<<<(N_NODES + 63) / 64, 256, 0, stream>>>(h, Wo, bout, out);
}